// Round 1
// baseline (216.866 us; speedup 1.0000x reference)
//
#include <hip/hip_runtime.h>
#include <hip/hip_bf16.h>

typedef unsigned short u16;
typedef __bf16 v8bf __attribute__((ext_vector_type(8)));
typedef float f32x4 __attribute__((ext_vector_type(4)));
typedef unsigned int u32x4 __attribute__((ext_vector_type(4)));

// Problem constants
constexpr int BATCH = 2048;
constexpr int DIM   = 512;
constexpr int NCLS  = 10000;
constexpr int NPAD  = 10112;   // 79 * 128

#define F_S     30.0f
#define F_COS_M 0.9800665778412416f
#define F_SIN_M 0.19866933079506122f
#define F_TH   (-0.9800665778412416f)
#define F_MM    0.03973386615901224f
#define F_EPS   0.1f

#define TILE 128
#define BK   32
#define LDK  40   // padded LDS stride (u16 units): 80B rows -> 2-way (free) bank aliasing

static __device__ __forceinline__ float clampf(float v, float lo, float hi) {
    return fminf(fmaxf(v, lo), hi);
}
static __device__ __forceinline__ u16 f2bf(float v) {
    __hip_bfloat16 h = __float2bfloat16(v);
    return __builtin_bit_cast(unsigned short, h);
}
// 256-thread block sum; sh must have >=4 floats
static __device__ __forceinline__ float blk_sum(float v, float* sh, int t) {
#pragma unroll
    for (int o = 32; o > 0; o >>= 1) v += __shfl_down(v, o, 64);
    __syncthreads();
    if ((t & 63) == 0) sh[t >> 6] = v;
    __syncthreads();
    return sh[0] + sh[1] + sh[2] + sh[3];
}

// ---------------- normalize x rows -> bf16 ----------------
__global__ __launch_bounds__(256) void norm_x_kernel(const float* __restrict__ src,
                                                     u16* __restrict__ dst) {
    __shared__ float sh[4];
    const int row = blockIdx.x, t = threadIdx.x;
    const float* p = src + (size_t)row * DIM;
    float x0 = p[t], x1 = p[t + 256];
    float s = blk_sum(x0 * x0 + x1 * x1, sh, t);
    float inv = 1.0f / fmaxf(sqrtf(s), 1e-12f);
    dst[(size_t)row * DIM + t]       = f2bf(x0 * inv);
    dst[(size_t)row * DIM + t + 256] = f2bf(x1 * inv);
}

// ---------------- normalize weight rows -> bf16 (rows >= NCLS zeroed) ----------------
__global__ __launch_bounds__(256) void norm_w_kernel(const float* __restrict__ w,
                                                     u16* __restrict__ dst) {
    __shared__ float sh[4];
    const int row = blockIdx.x, t = threadIdx.x;
    if (row >= NCLS) {  // uniform per block
        dst[(size_t)row * DIM + t] = 0;
        dst[(size_t)row * DIM + t + 256] = 0;
        return;
    }
    const float* p = w + (size_t)row * DIM;
    float x0 = p[t], x1 = p[t + 256];
    float s = blk_sum(x0 * x0 + x1 * x1, sh, t);
    float inv = 1.0f / fmaxf(sqrtf(s), 1e-12f);
    dst[(size_t)row * DIM + t]       = f2bf(x0 * inv);
    dst[(size_t)row * DIM + t + 256] = f2bf(x1 * inv);
}

// ---------------- gather weight_m[label], weight_n[label]; normalize -> bf16 ----------------
__global__ __launch_bounds__(256) void gather_norm_kernel(const float* __restrict__ wm,
                                                          const float* __restrict__ wn,
                                                          const int* __restrict__ label,
                                                          u16* __restrict__ dq,
                                                          u16* __restrict__ dk) {
    __shared__ float sh[8];
    const int i = blockIdx.x, t = threadIdx.x;
    const int g = label[i];
    const float* pq = wm + (size_t)g * DIM;
    const float* pk = wn + (size_t)g * DIM;
    float q0 = pq[t], q1 = pq[t + 256];
    float k0 = pk[t], k1 = pk[t + 256];
    float sq = blk_sum(q0 * q0 + q1 * q1, sh, t);
    float sk = blk_sum(k0 * k0 + k1 * k1, sh + 4, t);
    float iq = 1.0f / fmaxf(sqrtf(sq), 1e-12f);
    float ik = 1.0f / fmaxf(sqrtf(sk), 1e-12f);
    dq[(size_t)i * DIM + t]       = f2bf(q0 * iq);
    dq[(size_t)i * DIM + t + 256] = f2bf(q1 * iq);
    dk[(size_t)i * DIM + t]       = f2bf(k0 * ik);
    dk[(size_t)i * DIM + t + 256] = f2bf(k1 * ik);
}

// ---------------- AAM GEMM: logits = S*phi-adjusted(xn . wn^T); fused row Σexp / Σlogit ----------------
__global__ __launch_bounds__(256) void gemm_aam_kernel(const u16* __restrict__ A,   // [BATCH][DIM] bf16
                                                       const u16* __restrict__ B,   // [NPAD][DIM] bf16
                                                       const int* __restrict__ label,
                                                       float* __restrict__ sumexp,
                                                       float* __restrict__ sumlogit,
                                                       float* __restrict__ philab) {
    __shared__ __align__(16) u16 As[TILE * LDK];
    __shared__ __align__(16) u16 Bs[TILE * LDK];
    __shared__ float red_e[TILE];
    __shared__ float red_l[TILE];

    const int t = threadIdx.x;
    const int lane = t & 63, wave = t >> 6;
    const int wm = (wave >> 1) * 64, wn = (wave & 1) * 64;
    const int fr = lane & 15, quad = lane >> 4;
    const int bm = blockIdx.x, bn = blockIdx.y;
    const int srow = t >> 2, schunk = t & 3;

    if (t < TILE) { red_e[t] = 0.f; red_l[t] = 0.f; }

    const u16* ag = A + (size_t)(bm * TILE + srow) * DIM + schunk * 8;
    const u16* bg = B + (size_t)(bn * TILE + srow) * DIM + schunk * 8;
    u16* asw = &As[srow * LDK + schunk * 8];
    u16* bsw = &Bs[srow * LDK + schunk * 8];

    f32x4 acc[4][4] = {};

    for (int k0 = 0; k0 < DIM; k0 += BK) {
        u32x4 a0 = *(const u32x4*)(ag + k0);
        u32x4 a1 = *(const u32x4*)(ag + (size_t)64 * DIM + k0);
        u32x4 b0 = *(const u32x4*)(bg + k0);
        u32x4 b1 = *(const u32x4*)(bg + (size_t)64 * DIM + k0);
        *(u32x4*)asw = a0;
        *(u32x4*)(asw + 64 * LDK) = a1;
        *(u32x4*)bsw = b0;
        *(u32x4*)(bsw + 64 * LDK) = b1;
        __syncthreads();
        v8bf af[4], bf[4];
#pragma unroll
        for (int f = 0; f < 4; f++) {
            af[f] = __builtin_bit_cast(v8bf, *(const u32x4*)&As[(wm + f * 16 + fr) * LDK + quad * 8]);
            bf[f] = __builtin_bit_cast(v8bf, *(const u32x4*)&Bs[(wn + f * 16 + fr) * LDK + quad * 8]);
        }
#pragma unroll
        for (int i = 0; i < 4; i++)
#pragma unroll
            for (int j = 0; j < 4; j++)
                acc[i][j] = __builtin_amdgcn_mfma_f32_16x16x32_bf16(af[i], bf[j], acc[i][j], 0, 0, 0);
        __syncthreads();
    }

    // Epilogue: per-row partial Σexp(logit), Σlogit (no max-sub: logits<=30, sum<=1e17 fits fp32)
#pragma unroll
    for (int i = 0; i < 4; i++) {
#pragma unroll
        for (int r = 0; r < 4; r++) {
            const int ml = wm + i * 16 + quad * 4 + r;   // C/D row = quad*4+reg (m89/m91 verified)
            const int mg = bm * TILE + ml;
            const int lab = label[mg];
            float esum = 0.f, lsum = 0.f;
#pragma unroll
            for (int j = 0; j < 4; j++) {
                const int ng = bn * TILE + wn + j * 16 + fr;  // C/D col = lane&15
                if (ng < NCLS) {
                    float c = acc[i][j][r];
                    float logit;
                    if (ng == lab) {
                        float sine = sqrtf(clampf(1.f - c * c, 0.f, 1.f));
                        float phi = c * F_COS_M - sine * F_SIN_M;
                        float val = ((c - F_TH) > 0.f) ? phi : (c - F_MM);
                        logit = F_S * val;
                        philab[mg] = logit;   // unique writer
                    } else {
                        logit = F_S * c;
                    }
                    esum += __expf(logit);
                    lsum += logit;
                }
            }
#pragma unroll
            for (int off = 1; off < 16; off <<= 1) {
                esum += __shfl_xor(esum, off, 64);
                lsum += __shfl_xor(lsum, off, 64);
            }
            if (fr == 0) {
                atomicAdd(&red_e[ml], esum);
                atomicAdd(&red_l[ml], lsum);
            }
        }
    }
    __syncthreads();
    if (t < TILE) {
        atomicAdd(&sumexp[bm * TILE + t], red_e[t]);
        atomicAdd(&sumlogit[bm * TILE + t], red_l[t]);
    }
}

// ---------------- CC dual GEMM: sim = (xn.wq^T) * (xn.wk^T) elementwise ----------------
__global__ __launch_bounds__(256) void gemm_cc_kernel(const u16* __restrict__ A,
                                                      const u16* __restrict__ Bq,
                                                      const u16* __restrict__ Bk,
                                                      float* __restrict__ sim) {
    __shared__ __align__(16) u16 As[TILE * LDK];
    __shared__ __align__(16) u16 Qs[TILE * LDK];
    __shared__ __align__(16) u16 Ks[TILE * LDK];

    const int t = threadIdx.x;
    const int lane = t & 63, wave = t >> 6;
    const int wm = (wave >> 1) * 64, wn = (wave & 1) * 64;
    const int fr = lane & 15, quad = lane >> 4;
    const int bm = blockIdx.x, bn = blockIdx.y;
    const int srow = t >> 2, schunk = t & 3;

    const u16* ag = A  + (size_t)(bm * TILE + srow) * DIM + schunk * 8;
    const u16* qg = Bq + (size_t)(bn * TILE + srow) * DIM + schunk * 8;
    const u16* kg = Bk + (size_t)(bn * TILE + srow) * DIM + schunk * 8;
    u16* asw = &As[srow * LDK + schunk * 8];
    u16* qsw = &Qs[srow * LDK + schunk * 8];
    u16* ksw = &Ks[srow * LDK + schunk * 8];

    f32x4 aq[4][4] = {};
    f32x4 ak[4][4] = {};

    for (int k0 = 0; k0 < DIM; k0 += BK) {
        u32x4 a0 = *(const u32x4*)(ag + k0);
        u32x4 a1 = *(const u32x4*)(ag + (size_t)64 * DIM + k0);
        u32x4 q0 = *(const u32x4*)(qg + k0);
        u32x4 q1 = *(const u32x4*)(qg + (size_t)64 * DIM + k0);
        u32x4 k0v = *(const u32x4*)(kg + k0);
        u32x4 k1v = *(const u32x4*)(kg + (size_t)64 * DIM + k0);
        *(u32x4*)asw = a0; *(u32x4*)(asw + 64 * LDK) = a1;
        *(u32x4*)qsw = q0; *(u32x4*)(qsw + 64 * LDK) = q1;
        *(u32x4*)ksw = k0v; *(u32x4*)(ksw + 64 * LDK) = k1v;
        __syncthreads();
        v8bf af[4], qf[4], kf[4];
#pragma unroll
        for (int f = 0; f < 4; f++) {
            af[f] = __builtin_bit_cast(v8bf, *(const u32x4*)&As[(wm + f * 16 + fr) * LDK + quad * 8]);
            qf[f] = __builtin_bit_cast(v8bf, *(const u32x4*)&Qs[(wn + f * 16 + fr) * LDK + quad * 8]);
            kf[f] = __builtin_bit_cast(v8bf, *(const u32x4*)&Ks[(wn + f * 16 + fr) * LDK + quad * 8]);
        }
#pragma unroll
        for (int i = 0; i < 4; i++)
#pragma unroll
            for (int j = 0; j < 4; j++) {
                aq[i][j] = __builtin_amdgcn_mfma_f32_16x16x32_bf16(af[i], qf[j], aq[i][j], 0, 0, 0);
                ak[i][j] = __builtin_amdgcn_mfma_f32_16x16x32_bf16(af[i], kf[j], ak[i][j], 0, 0, 0);
            }
        __syncthreads();
    }

#pragma unroll
    for (int i = 0; i < 4; i++)
#pragma unroll
        for (int r = 0; r < 4; r++) {
            const int mg = bm * TILE + wm + i * 16 + quad * 4 + r;
#pragma unroll
            for (int j = 0; j < 4; j++) {
                const int ng = bn * TILE + wn + j * 16 + fr;
                sim[(size_t)mg * BATCH + ng] = aq[i][j][r] * ak[i][j][r];
            }
        }
}

// ---------------- CC row stats: ap_m, ap -> cos_apm/sin_apm/logit_neg ----------------
__global__ __launch_bounds__(256) void cc_rowstats_kernel(const float* __restrict__ sim,
                                                          const int* __restrict__ label,
                                                          float* __restrict__ cos_apm,
                                                          float* __restrict__ sin_apm,
                                                          float* __restrict__ logneg) {
    __shared__ float sh[8];
    __shared__ float s_ap;
    const int i = blockIdx.x, t = threadIdx.x;
    const int li = label[i];
    float msum = 0.f, mcnt = 0.f;
    for (int j = t; j < BATCH; j += 256) {
        float s = sim[(size_t)i * BATCH + j];
        if (label[j] == li) { msum += s; mcnt += 1.f; }
        if (j == i) s_ap = s;
    }
    msum = blk_sum(msum, sh, t);
    mcnt = blk_sum(mcnt, sh + 4, t);
    if (t == 0) {
        float apm = msum / mcnt;      // mcnt >= 1 (diagonal)
        float cam = clampf(apm, 0.f, 1.f);
        float sam = sqrtf(clampf(1.f - cam, 0.f, 1.f));
        cos_apm[i] = cam;
        sin_apm[i] = sam;
        float ap = s_ap;
        float cap = clampf(ap, 0.f, 1.f);
        float sap = sqrtf(clampf(1.f - cap, 0.f, 1.f));
        float ppc = cap * cam - sap * sam;
        float pps = sqrtf(clampf(1.f - ppc, 0.f, 1.f));
        float phi_pm = ppc * F_COS_M - pps * F_SIN_M;
        logneg[i] = 1.f - phi_pm;
    }
}

// ---------------- CC masked global Σexp(phi_nm) ----------------
__global__ __launch_bounds__(256) void cc_lse_kernel(const float* __restrict__ sim,
                                                     const int* __restrict__ label,
                                                     const float* __restrict__ cos_apm,
                                                     const float* __restrict__ sin_apm,
                                                     float* __restrict__ zn) {
    __shared__ float sh[4];
    const int i = blockIdx.x, t = threadIdx.x;
    const int li = label[i];
    float acc = 0.f;
    for (int j = t; j < BATCH; j += 256) {
        if (label[j] != li) {
            float s = sim[(size_t)i * BATCH + j];
            float can = clampf(s, 0.f, 1.f);
            float san = sqrtf(clampf(1.f - can, 0.f, 1.f));
            float pns = san * cos_apm[j] + can * sin_apm[j];   // broadcast by COLUMN j
            float pnc = sqrtf(clampf(1.f - pns, 0.f, 1.f));
            float phi_nm = pns * F_COS_M - pnc * F_SIN_M;      // bounded [-0.2, 1.96] -> no max-sub
            acc += __expf(phi_nm);
        }
    }
    acc = blk_sum(acc, sh, t);
    if (t == 0) atomicAdd(zn, acc);
}

// ---------------- finalize: aam_loss + cc_loss ----------------
__global__ __launch_bounds__(256) void finalize_kernel(const float* __restrict__ sumexp,
                                                       const float* __restrict__ sumlogit,
                                                       const float* __restrict__ philab,
                                                       const float* __restrict__ logneg,
                                                       const float* __restrict__ zn,
                                                       float* __restrict__ out) {
    __shared__ float sh[8];
    const int t = threadIdx.x;
    float accA = 0.f, accN = 0.f;
    for (int i = t; i < BATCH; i += 256) {
        float lse = logf(sumexp[i]);
        accA += (1.f - F_EPS) * (philab[i] - lse) +
                (F_EPS / (float)NCLS) * (sumlogit[i] - (float)NCLS * lse);
        accN += __expf(logneg[i]);
    }
    accA = blk_sum(accA, sh, t);
    accN = blk_sum(accN, sh + 4, t);
    if (t == 0) {
        float aam = -accA / (float)BATCH;
        float lse_neg = logf(accN);
        float lse_n = logf(zn[0]);
        float z = lse_n + lse_neg;
        float cc = (z > 0.f) ? (z + log1pf(__expf(-z))) : log1pf(__expf(z));
        out[0] = aam + cc;
    }
}

extern "C" void kernel_launch(void* const* d_in, const int* in_sizes, int n_in,
                              void* d_out, int out_size, void* d_ws, size_t ws_size,
                              hipStream_t stream) {
    const float* x        = (const float*)d_in[0];
    const int*   label    = (const int*)d_in[1];
    const float* weight   = (const float*)d_in[2];
    const float* weight_m = (const float*)d_in[3];
    const float* weight_n = (const float*)d_in[4];
    float* out = (float*)d_out;
    char* ws = (char*)d_ws;

    // ws layout (bytes)
    const size_t o_xnb  = 0;                                   // bf16 [BATCH*DIM]   2 MB
    const size_t o_wb   = o_xnb + (size_t)BATCH * DIM * 2;     // bf16 [NPAD*DIM]   10.35 MB
    const size_t o_wqb  = o_wb  + (size_t)NPAD * DIM * 2;      // bf16 [BATCH*DIM]   2 MB
    const size_t o_wkb  = o_wqb + (size_t)BATCH * DIM * 2;     // bf16 [BATCH*DIM]   2 MB
    const size_t o_sim  = o_wkb + (size_t)BATCH * DIM * 2;     // f32  [BATCH*BATCH] 16.8 MB
    const size_t o_misc = o_sim + (size_t)BATCH * BATCH * 4;

    u16* xnb = (u16*)(ws + o_xnb);
    u16* wb  = (u16*)(ws + o_wb);
    u16* wqb = (u16*)(ws + o_wqb);
    u16* wkb = (u16*)(ws + o_wkb);
    float* sim = (float*)(ws + o_sim);
    float* mf = (float*)(ws + o_misc);
    float* sumexp   = mf;
    float* sumlogit = mf + 2048;
    float* philab   = mf + 4096;
    float* cos_apm  = mf + 6144;
    float* sin_apm  = mf + 8192;
    float* logneg   = mf + 10240;
    float* zn       = mf + 12288;

    // zero accumulators (sumexp, sumlogit, ..., zn)
    hipMemsetAsync(mf, 0, (12288 + 64) * sizeof(float), stream);

    norm_x_kernel<<<BATCH, 256, 0, stream>>>(x, xnb);
    norm_w_kernel<<<NPAD, 256, 0, stream>>>(weight, wb);
    gather_norm_kernel<<<BATCH, 256, 0, stream>>>(weight_m, weight_n, label, wqb, wkb);

    dim3 g_aam(BATCH / TILE, NPAD / TILE);   // (16, 79)
    gemm_aam_kernel<<<g_aam, 256, 0, stream>>>(xnb, wb, label, sumexp, sumlogit, philab);

    dim3 g_cc(BATCH / TILE, BATCH / TILE);   // (16, 16)
    gemm_cc_kernel<<<g_cc, 256, 0, stream>>>(xnb, wqb, wkb, sim);

    cc_rowstats_kernel<<<BATCH, 256, 0, stream>>>(sim, label, cos_apm, sin_apm, logneg);
    cc_lse_kernel<<<BATCH, 256, 0, stream>>>(sim, label, cos_apm, sin_apm, zn);
    finalize_kernel<<<1, 256, 0, stream>>>(sumexp, sumlogit, philab, logneg, zn, out);
}